// Round 1
// baseline (238.929 us; speedup 1.0000x reference)
//
#include <hip/hip_runtime.h>
#include <math.h>

#define R_RAYS 65536
#define S_SAMP 128
#define NSLOTS 1024
// out layout: [0]=d_rgb, [1..R]=d_op, [1+R]=d_eik, [2+R .. 1+2R]=d_dist

__global__ void init_ws_kernel(float* __restrict__ w) {
    int i = blockIdx.x * blockDim.x + threadIdx.x;
    if (i < 2 * NSLOTS) w[i] = 0.f;
}

__device__ __forceinline__ float wave_incl_scan(float x, int lane) {
#pragma unroll
    for (int off = 1; off < 64; off <<= 1) {
        float v = __shfl_up(x, off, 64);
        if (lane >= off) x += v;
    }
    return x;
}

__global__ __launch_bounds__(128) void nerf_main_kernel(
    const float* __restrict__ rgb, const float* __restrict__ tgt,
    const float* __restrict__ opacity, const float* __restrict__ grad,
    const float* __restrict__ ws, const float* __restrict__ deltas,
    const float* __restrict__ ts, const int* __restrict__ rays_a,
    float* __restrict__ out, float* __restrict__ partials)
{
    const int r    = blockIdx.x;
    const int tid  = threadIdx.x;
    const int lane = tid & 63;
    const int wave = tid >> 6;

    const int ridx  = rays_a[3 * r + 0];
    const int start = rays_a[3 * r + 1];
    const int i = start + tid;

    const float w = ws[i];
    const float t = ts[i];
    const float d = deltas[i];
    const float wt = w * t;

    // segment-local exclusive prefix sums of w and w*t (128 = 2 waves)
    float iw  = wave_incl_scan(w, lane);
    float iwt = wave_incl_scan(wt, lane);
    __shared__ float s_w[2], s_wt[2];
    if (lane == 63) { s_w[wave] = iw; s_wt[wave] = iwt; }
    __syncthreads();
    const float bw  = (wave == 1) ? s_w[0]  : 0.f;
    const float bwt = (wave == 1) ? s_wt[0] : 0.f;
    const float ew  = iw  - w  + bw;
    const float ewt = iwt - wt + bwt;

    float per = 2.f * w * (t * ew - ewt) + w * w * d * (1.f / 3.f);

    // eikonal for grad row i (AoS float3)
    const float gx = grad[3 * i + 0];
    const float gy = grad[3 * i + 1];
    const float gz = grad[3 * i + 2];
    const float nrm = sqrtf(gx * gx + gy * gy + gz * gz);
    float ek = (nrm - 1.f) * (nrm - 1.f);

    // block reductions (per-wave shuffle, then 2-wave LDS combine)
#pragma unroll
    for (int off = 32; off > 0; off >>= 1) {
        per += __shfl_down(per, off, 64);
        ek  += __shfl_down(ek,  off, 64);
    }
    __shared__ float s_per[2], s_ek[2];
    if (lane == 0) { s_per[wave] = per; s_ek[wave] = ek; }
    __syncthreads();

    if (tid == 0) {
        out[2 + R_RAYS + ridx] = 0.001f * (s_per[0] + s_per[1]);   // L_DIST * per_row
    } else if (tid == 1) {
        atomicAdd(&partials[r & (NSLOTS - 1)], s_ek[0] + s_ek[1]);
    } else if (tid == 2) {
        const float op = opacity[r];
        out[1 + r] = 0.05f * (-op * logf(op));                      // L_OP * entropy
    } else if (tid == 3) {
        float srgb = 0.f;
#pragma unroll
        for (int c = 0; c < 3; ++c) {
            const float diff = fabsf(rgb[3 * r + c] - tgt[3 * r + c]);
            srgb += (diff < 1.f) ? 0.5f * diff * diff : (diff - 0.5f);
        }
        atomicAdd(&partials[NSLOTS + (r & (NSLOTS - 1))], srgb);
    }
}

__global__ __launch_bounds__(1024) void nerf_final_kernel(
    const float* __restrict__ partials, float* __restrict__ out)
{
    const int tid  = threadIdx.x;
    const int lane = tid & 63;
    const int wave = tid >> 6;

    float ek = partials[tid];
    float rg = partials[NSLOTS + tid];
#pragma unroll
    for (int off = 32; off > 0; off >>= 1) {
        ek += __shfl_down(ek, off, 64);
        rg += __shfl_down(rg, off, 64);
    }
    __shared__ float s_ek[16], s_rg[16];
    if (lane == 0) { s_ek[wave] = ek; s_rg[wave] = rg; }
    __syncthreads();
    if (tid == 0) {
        float tek = 0.f, trg = 0.f;
#pragma unroll
        for (int j = 0; j < 16; ++j) { tek += s_ek[j]; trg += s_rg[j]; }
        out[0]          = trg / (3.f * (float)R_RAYS);                       // d_rgb mean
        out[1 + R_RAYS] = 0.1f * tek / ((float)R_RAYS * (float)S_SAMP);     // d_eik
    }
}

extern "C" void kernel_launch(void* const* d_in, const int* in_sizes, int n_in,
                              void* d_out, int out_size, void* d_ws, size_t ws_size,
                              hipStream_t stream) {
    const float* rgb     = (const float*)d_in[0];
    const float* tgt     = (const float*)d_in[1];
    const float* opacity = (const float*)d_in[2];
    const float* grad    = (const float*)d_in[3];
    const float* ws      = (const float*)d_in[4];
    const float* deltas  = (const float*)d_in[5];
    const float* ts      = (const float*)d_in[6];
    const int*   rays_a  = (const int*)d_in[7];
    float* out      = (float*)d_out;
    float* partials = (float*)d_ws;

    init_ws_kernel<<<(2 * NSLOTS + 255) / 256, 256, 0, stream>>>(partials);
    nerf_main_kernel<<<R_RAYS, 128, 0, stream>>>(rgb, tgt, opacity, grad, ws,
                                                 deltas, ts, rays_a, out, partials);
    nerf_final_kernel<<<1, 1024, 0, stream>>>(partials, out);
}

// Round 2
// 230.621 us; speedup vs baseline: 1.0360x; 1.0360x over previous
//
#include <hip/hip_runtime.h>
#include <math.h>

#define R_RAYS 65536
#define S_SAMP 128
#define RAYS_PER_BLOCK 8
#define NB (R_RAYS / RAYS_PER_BLOCK)   // 8192 blocks
// out layout: [0]=d_rgb, [1..R]=d_op, [1+R]=d_eik, [2+R .. 1+2R]=d_dist

__global__ __launch_bounds__(256) void nerf_main_kernel(
    const float* __restrict__ rgb, const float* __restrict__ tgt,
    const float* __restrict__ opacity, const float* __restrict__ grad,
    const float* __restrict__ ws, const float* __restrict__ deltas,
    const float* __restrict__ ts, const int* __restrict__ rays_a,
    float* __restrict__ out, float* __restrict__ partials)
{
    const int tid  = threadIdx.x;      // 0..255
    const int wave = tid >> 6;         // 0..3
    const int lane = tid & 63;
    const int grp  = tid >> 5;         // 0..7 : 32-lane group == one ray
    const int l32  = tid & 31;
    const int b    = blockIdx.x;
    const int r    = b * RAYS_PER_BLOCK + grp;

    const int ridx  = rays_a[3 * r + 0];
    const int start = rays_a[3 * r + 1];          // == r*128 by construction
    const int i0    = start + l32 * 4;            // 4 consecutive samples/lane

    // ---- vectorized sample loads (16B/lane each) ----
    const float4 w4 = *(const float4*)(ws + i0);
    const float4 t4 = *(const float4*)(ts + i0);
    const float4 d4 = *(const float4*)(deltas + i0);
    const float wv[4] = { w4.x, w4.y, w4.z, w4.w };
    const float tv[4] = { t4.x, t4.y, t4.z, t4.w };
    const float dv[4] = { d4.x, d4.y, d4.z, d4.w };

    float wtv[4];
    float sw = 0.f, swt = 0.f;
#pragma unroll
    for (int j = 0; j < 4; ++j) { wtv[j] = wv[j] * tv[j]; sw += wv[j]; swt += wtv[j]; }

    // ---- width-32 inclusive scan of per-lane sums (ray-local) ----
    float isw = sw, iswt = swt;
#pragma unroll
    for (int off = 1; off < 32; off <<= 1) {
        const float a = __shfl_up(isw,  off, 32);
        const float c = __shfl_up(iswt, off, 32);
        if (l32 >= off) { isw += a; iswt += c; }
    }
    float ew  = isw  - sw;    // exclusive prefix entering this lane
    float ewt = iswt - swt;

    float per = 0.f;
#pragma unroll
    for (int j = 0; j < 4; ++j) {
        per += 2.f * wv[j] * (tv[j] * ew - ewt) + wv[j] * wv[j] * dv[j] * (1.f / 3.f);
        ew  += wv[j];
        ewt += wtv[j];
    }

    // ---- eikonal: 4 grad rows = 12 floats = 3 aligned float4 loads ----
    const float* gp = grad + 3 * i0;              // float offset 384r + 12*l32 (16B aligned)
    const float4 g0 = *(const float4*)(gp + 0);
    const float4 g1 = *(const float4*)(gp + 4);
    const float4 g2 = *(const float4*)(gp + 8);
    float ek = 0.f;
    {
        float n;
        n = sqrtf(g0.x*g0.x + g0.y*g0.y + g0.z*g0.z); ek += (n-1.f)*(n-1.f);
        n = sqrtf(g0.w*g0.w + g1.x*g1.x + g1.y*g1.y); ek += (n-1.f)*(n-1.f);
        n = sqrtf(g1.z*g1.z + g1.w*g1.w + g2.x*g2.x); ek += (n-1.f)*(n-1.f);
        n = sqrtf(g2.y*g2.y + g2.z*g2.z + g2.w*g2.w); ek += (n-1.f)*(n-1.f);
    }

    // ---- per-ray reduction of per (width 32) ----
#pragma unroll
    for (int off = 16; off > 0; off >>= 1) per += __shfl_down(per, off, 32);

    // ---- wave reduction of ek (width 64) ----
#pragma unroll
    for (int off = 32; off > 0; off >>= 1) ek += __shfl_down(ek, off, 64);

    __shared__ float s_ek[4], s_rg[8];
    if (lane == 0) s_ek[wave] = ek;

    if (l32 == 0) {
        out[2 + R_RAYS + ridx] = 0.001f * per;                   // L_DIST * per_row
    } else if (l32 == 1) {
        const float op = opacity[r];
        out[1 + r] = 0.05f * (-op * logf(op));                   // L_OP * entropy
    } else if (l32 == 2) {
        float srgb = 0.f;
#pragma unroll
        for (int c = 0; c < 3; ++c) {
            const float diff = fabsf(rgb[3 * r + c] - tgt[3 * r + c]);
            srgb += (diff < 1.f) ? 0.5f * diff * diff : (diff - 0.5f);
        }
        s_rg[grp] = srgb;
    }
    __syncthreads();

    if (tid == 0) {
        float bek = s_ek[0] + s_ek[1] + s_ek[2] + s_ek[3];
        float brg = 0.f;
#pragma unroll
        for (int j = 0; j < 8; ++j) brg += s_rg[j];
        partials[b]      = bek;                                  // no init needed
        partials[NB + b] = brg;
    }
}

__global__ __launch_bounds__(1024) void nerf_final_kernel(
    const float* __restrict__ partials, float* __restrict__ out)
{
    const int tid  = threadIdx.x;
    const int lane = tid & 63;
    const int wave = tid >> 6;

    float ek = 0.f, rg = 0.f;
#pragma unroll
    for (int k = 0; k < NB / 1024; ++k) {
        ek += partials[tid + k * 1024];
        rg += partials[NB + tid + k * 1024];
    }
#pragma unroll
    for (int off = 32; off > 0; off >>= 1) {
        ek += __shfl_down(ek, off, 64);
        rg += __shfl_down(rg, off, 64);
    }
    __shared__ float s_ek[16], s_rg[16];
    if (lane == 0) { s_ek[wave] = ek; s_rg[wave] = rg; }
    __syncthreads();
    if (tid == 0) {
        float tek = 0.f, trg = 0.f;
#pragma unroll
        for (int j = 0; j < 16; ++j) { tek += s_ek[j]; trg += s_rg[j]; }
        out[0]          = trg / (3.f * (float)R_RAYS);                    // d_rgb
        out[1 + R_RAYS] = 0.1f * tek / ((float)R_RAYS * (float)S_SAMP);   // d_eik
    }
}

extern "C" void kernel_launch(void* const* d_in, const int* in_sizes, int n_in,
                              void* d_out, int out_size, void* d_ws, size_t ws_size,
                              hipStream_t stream) {
    const float* rgb     = (const float*)d_in[0];
    const float* tgt     = (const float*)d_in[1];
    const float* opacity = (const float*)d_in[2];
    const float* grad    = (const float*)d_in[3];
    const float* ws      = (const float*)d_in[4];
    const float* deltas  = (const float*)d_in[5];
    const float* ts      = (const float*)d_in[6];
    const int*   rays_a  = (const int*)d_in[7];
    float* out      = (float*)d_out;
    float* partials = (float*)d_ws;

    nerf_main_kernel<<<NB, 256, 0, stream>>>(rgb, tgt, opacity, grad, ws,
                                             deltas, ts, rays_a, out, partials);
    nerf_final_kernel<<<1, 1024, 0, stream>>>(partials, out);
}

// Round 3
// 229.399 us; speedup vs baseline: 1.0415x; 1.0053x over previous
//
#include <hip/hip_runtime.h>
#include <math.h>

#define R_RAYS 65536
#define S_SAMP 128
#define RAYS_PER_BLOCK 8
#define NB (R_RAYS / RAYS_PER_BLOCK)   // 8192 blocks
// out layout: [0]=d_rgb, [1..R]=d_op, [1+R]=d_eik, [2+R .. 1+2R]=d_dist

// x + dpp_move(x) with compile-time ctrl/row_mask; old=0 + bound_ctrl=1 makes
// masked-off / out-of-range lanes contribute 0.
template <int CTRL, int ROW_MASK>
__device__ __forceinline__ float dpp_add(float x) {
    int moved = __builtin_amdgcn_update_dpp(0, __float_as_int(x), CTRL, ROW_MASK, 0xF, true);
    return x + __int_as_float(moved);
}

// inclusive scan over each 32-lane half (5 VALU DPP adds, no DS ops)
__device__ __forceinline__ float scan32(float x) {
    x = dpp_add<0x111, 0xF>(x);  // row_shr:1
    x = dpp_add<0x112, 0xF>(x);  // row_shr:2
    x = dpp_add<0x114, 0xF>(x);  // row_shr:4
    x = dpp_add<0x118, 0xF>(x);  // row_shr:8
    x = dpp_add<0x142, 0xA>(x);  // row_bcast:15 -> rows 1,3 (bridge 16->32)
    return x;                    // lane31/63 of each half hold the half-total
}

// full-wave reduction; lane 63 ends with the 64-lane total
__device__ __forceinline__ float reduce64(float x) {
    x = dpp_add<0x111, 0xF>(x);
    x = dpp_add<0x112, 0xF>(x);
    x = dpp_add<0x114, 0xF>(x);
    x = dpp_add<0x118, 0xF>(x);
    x = dpp_add<0x142, 0xA>(x);  // row_bcast:15
    x = dpp_add<0x143, 0xC>(x);  // row_bcast:31 -> rows 2,3
    return x;
}

__global__ __launch_bounds__(256) void nerf_main_kernel(
    const float* __restrict__ rgb, const float* __restrict__ tgt,
    const float* __restrict__ opacity, const float* __restrict__ grad,
    const float* __restrict__ ws, const float* __restrict__ deltas,
    const float* __restrict__ ts, const int* __restrict__ rays_a,
    float* __restrict__ out, float* __restrict__ partials)
{
    const int tid  = threadIdx.x;      // 0..255
    const int wave = tid >> 6;         // 0..3
    const int lane = tid & 63;
    const int grp  = tid >> 5;         // 0..7 : 32-lane group == one ray
    const int l32  = tid & 31;
    const int b    = blockIdx.x;
    const int r    = b * RAYS_PER_BLOCK + grp;

    // starts are arange(R)*S by construction -> no load on the address path
    const int i0 = r * S_SAMP + l32 * 4;
    const int v0 = r * (S_SAMP / 4) + l32;         // float4 index

    // ---- vectorized sample loads (16B/lane each), independent, issue early ----
    const float4 w4 = ((const float4*)ws)[v0];
    const float4 t4 = ((const float4*)ts)[v0];
    const float4 d4 = ((const float4*)deltas)[v0];
    // grad rows for samples i0..i0+3 : 12 floats = 3 aligned float4 loads
    const float* gp = grad + 3 * i0;
    const float4 g0 = *(const float4*)(gp + 0);
    const float4 g1 = *(const float4*)(gp + 4);
    const float4 g2 = *(const float4*)(gp + 8);
    // ridx only needed for the final scatter (off critical path)
    const int ridx = rays_a[3 * r];

    const float wv[4] = { w4.x, w4.y, w4.z, w4.w };
    const float tv[4] = { t4.x, t4.y, t4.z, t4.w };
    const float dv[4] = { d4.x, d4.y, d4.z, d4.w };

    float wtv[4];
    float sw = 0.f, swt = 0.f;
#pragma unroll
    for (int j = 0; j < 4; ++j) { wtv[j] = wv[j] * tv[j]; sw += wv[j]; swt += wtv[j]; }

    // ---- ray-local (width-32) inclusive scan via DPP ----
    const float isw  = scan32(sw);
    const float iswt = scan32(swt);
    float ew  = isw  - sw;    // exclusive prefix entering this lane
    float ewt = iswt - swt;

    float per = 0.f;
#pragma unroll
    for (int j = 0; j < 4; ++j) {
        per += 2.f * wv[j] * (tv[j] * ew - ewt) + wv[j] * wv[j] * dv[j] * (1.f / 3.f);
        ew  += wv[j];
        ewt += wtv[j];
    }

    // ---- eikonal for the 4 grad rows ----
    float ek = 0.f;
    {
        float n;
        n = sqrtf(g0.x*g0.x + g0.y*g0.y + g0.z*g0.z); ek += (n-1.f)*(n-1.f);
        n = sqrtf(g0.w*g0.w + g1.x*g1.x + g1.y*g1.y); ek += (n-1.f)*(n-1.f);
        n = sqrtf(g1.z*g1.z + g1.w*g1.w + g2.x*g2.x); ek += (n-1.f)*(n-1.f);
        n = sqrtf(g2.y*g2.y + g2.z*g2.z + g2.w*g2.w); ek += (n-1.f)*(n-1.f);
    }

    // per-ray total: scan32 leaves it in lane 31 of each half
    const float per_scan = scan32(per);
    // ek wave total in lane 63
    const float ek_tot = reduce64(ek);

    __shared__ float s_ek[4], s_rg[8];
    if (lane == 63) s_ek[wave] = ek_tot;

    if (l32 == 31) {
        out[2 + R_RAYS + ridx] = 0.001f * per_scan;              // L_DIST * per_row
    } else if (l32 == 1) {
        const float op = opacity[r];
        out[1 + r] = 0.05f * (-op * logf(op));                   // L_OP * entropy
    } else if (l32 == 2) {
        float srgb = 0.f;
#pragma unroll
        for (int c = 0; c < 3; ++c) {
            const float diff = fabsf(rgb[3 * r + c] - tgt[3 * r + c]);
            srgb += (diff < 1.f) ? 0.5f * diff * diff : (diff - 0.5f);
        }
        s_rg[grp] = srgb;
    }
    __syncthreads();

    if (tid == 0) {
        float bek = s_ek[0] + s_ek[1] + s_ek[2] + s_ek[3];
        float brg = 0.f;
#pragma unroll
        for (int j = 0; j < 8; ++j) brg += s_rg[j];
        partials[b]      = bek;
        partials[NB + b] = brg;
    }
}

__global__ __launch_bounds__(1024) void nerf_final_kernel(
    const float* __restrict__ partials, float* __restrict__ out)
{
    const int tid  = threadIdx.x;
    const int lane = tid & 63;
    const int wave = tid >> 6;

    float ek = 0.f, rg = 0.f;
#pragma unroll
    for (int k = 0; k < NB / 1024; ++k) {
        ek += partials[tid + k * 1024];
        rg += partials[NB + tid + k * 1024];
    }
    ek = reduce64(ek);
    rg = reduce64(rg);
    __shared__ float s_ek[16], s_rg[16];
    if (lane == 63) { s_ek[wave] = ek; s_rg[wave] = rg; }
    __syncthreads();
    if (tid == 0) {
        float tek = 0.f, trg = 0.f;
#pragma unroll
        for (int j = 0; j < 16; ++j) { tek += s_ek[j]; trg += s_rg[j]; }
        out[0]          = trg / (3.f * (float)R_RAYS);                    // d_rgb
        out[1 + R_RAYS] = 0.1f * tek / ((float)R_RAYS * (float)S_SAMP);   // d_eik
    }
}

extern "C" void kernel_launch(void* const* d_in, const int* in_sizes, int n_in,
                              void* d_out, int out_size, void* d_ws, size_t ws_size,
                              hipStream_t stream) {
    const float* rgb     = (const float*)d_in[0];
    const float* tgt     = (const float*)d_in[1];
    const float* opacity = (const float*)d_in[2];
    const float* grad    = (const float*)d_in[3];
    const float* ws      = (const float*)d_in[4];
    const float* deltas  = (const float*)d_in[5];
    const float* ts      = (const float*)d_in[6];
    const int*   rays_a  = (const int*)d_in[7];
    float* out      = (float*)d_out;
    float* partials = (float*)d_ws;

    nerf_main_kernel<<<NB, 256, 0, stream>>>(rgb, tgt, opacity, grad, ws,
                                             deltas, ts, rays_a, out, partials);
    nerf_final_kernel<<<1, 1024, 0, stream>>>(partials, out);
}